// Round 1
// baseline (2220.442 us; speedup 1.0000x reference)
//
#include <hip/hip_runtime.h>
#include <math.h>

#define BATCH 8
#define CHAN 256
#define HH 128
#define WW 128
#define NMASK 100
#define HWSZ (HH*WW)
#define KD 128
#define SPLIT 16
#define GN 25

// d_out layout: [logits 800][kernel 102400][scores 800][iam 13107200]
#define OFF_LOGITS 0
#define OFF_KERNEL 800
#define OFF_SCORES (800 + 800*KD)
#define OFF_IAM    (OFF_SCORES + 800)

// ---------------- conv 3x3, pad 1 ----------------
// grid (4 h-tiles, 25 n-groups, 8 batch), 256 threads
__global__ __launch_bounds__(256) void conv_kernel(
    const float* __restrict__ feat, const float* __restrict__ cw,
    const float* __restrict__ cb, float* __restrict__ out_iam)
{
  const int h0 = blockIdx.x * 32;
  const int n0 = blockIdx.y * 4;
  const int b  = blockIdx.z;
  const int t  = threadIdx.x;
  const int tx = t & 31, ty = t >> 5;

  __shared__ float lds[34*132];

  float acc[4][4][4];  // [nn][i][j]
  #pragma unroll
  for (int a=0;a<4;a++)
    #pragma unroll
    for (int i=0;i<4;i++)
      #pragma unroll
      for (int j=0;j<4;j++) acc[a][i][j]=0.f;

  const float* fb = feat + (size_t)b*CHAN*HWSZ;

  for (int c=0;c<CHAN;c++){
    __syncthreads();
    for (int e=t; e<34*132; e+=256){
      int r  = e / 132;
      int cc = e - r*132;
      int y  = h0 - 1 + r;
      int x  = cc - 1;
      float v = 0.f;
      if ((unsigned)y < 128u && (unsigned)x < 128u)
        v = fb[c*HWSZ + y*WW + x];
      lds[e] = v;
    }
    __syncthreads();
    // block-uniform weights -> scalar loads
    float wv[4][9];
    #pragma unroll
    for (int nn=0;nn<4;nn++){
      const float* wp = cw + ((size_t)(n0+nn)*CHAN + c)*9;
      #pragma unroll
      for (int q=0;q<9;q++) wv[nn][q] = wp[q];
    }
    float pr[6][8];
    #pragma unroll
    for (int rr=0;rr<6;rr++){
      const float4 a0 = *(const float4*)&lds[(ty*4+rr)*132 + tx*4];
      const float4 a1 = *(const float4*)&lds[(ty*4+rr)*132 + tx*4 + 4];
      pr[rr][0]=a0.x; pr[rr][1]=a0.y; pr[rr][2]=a0.z; pr[rr][3]=a0.w;
      pr[rr][4]=a1.x; pr[rr][5]=a1.y; pr[rr][6]=a1.z; pr[rr][7]=a1.w;
    }
    #pragma unroll
    for (int nn=0;nn<4;nn++)
      #pragma unroll
      for (int kh=0;kh<3;kh++)
        #pragma unroll
        for (int kw=0;kw<3;kw++){
          const float wgt = wv[nn][kh*3+kw];
          #pragma unroll
          for (int i=0;i<4;i++)
            #pragma unroll
            for (int j=0;j<4;j++)
              acc[nn][i][j] = fmaf(wgt, pr[i+kh][j+kw], acc[nn][i][j]);
        }
  }
  #pragma unroll
  for (int nn=0;nn<4;nn++){
    const float bias = cb[n0+nn];
    #pragma unroll
    for (int i=0;i<4;i++){
      float4 v;
      v.x = acc[nn][i][0]+bias; v.y=acc[nn][i][1]+bias;
      v.z = acc[nn][i][2]+bias; v.w=acc[nn][i][3]+bias;
      const int h = h0 + ty*4 + i;
      *(float4*)&out_iam[((size_t)b*NMASK + n0+nn)*HWSZ + h*WW + tx*4] = v;
    }
  }
}

// ---------------- softmax row stats (max, 1/sumexp) ----------------
__global__ __launch_bounds__(256) void softmax_stats_kernel(
    const float* __restrict__ iam, float* __restrict__ rowmax, float* __restrict__ rowinv)
{
  const int row = blockIdx.x;     // b*100+n
  const int t = threadIdx.x;
  const float* p = iam + (size_t)row*HWSZ;
  __shared__ float red[256];
  float m = -1e30f;
  for (int it=0; it<16; it++){
    float4 v = *(const float4*)&p[(it*256+t)*4];
    m = fmaxf(m, fmaxf(fmaxf(v.x,v.y), fmaxf(v.z,v.w)));
  }
  red[t] = m; __syncthreads();
  for (int s=128;s>0;s>>=1){ if (t<s) red[t]=fmaxf(red[t],red[t+s]); __syncthreads(); }
  m = red[0]; __syncthreads();
  float sum=0.f;
  for (int it=0; it<16; it++){
    float4 v = *(const float4*)&p[(it*256+t)*4];
    sum += expf(v.x-m)+expf(v.y-m)+expf(v.z-m)+expf(v.w-m);
  }
  red[t]=sum; __syncthreads();
  for (int s=128;s>0;s>>=1){ if (t<s) red[t]+=red[t+s]; __syncthreads(); }
  if (t==0){ rowmax[row]=m; rowinv[row]=1.0f/red[0]; }
}

// ---------------- einsum: inst0[b,n,c] = sum_p prob[b,n,p]*feat[b,c,p] ----------------
// grid (16 k-splits, 4 n-groups, 8 batch), thread = channel c
__global__ __launch_bounds__(256) void einsum_kernel(
  const float* __restrict__ feat, const float* __restrict__ iam,
  const float* __restrict__ rowmax, const float* __restrict__ rowinv,
  float* __restrict__ partial)
{
  const int s = blockIdx.x;
  const int g = blockIdx.y;
  const int b = blockIdx.z;
  const int t = threadIdx.x;
  const int k0 = s*1024;
  __shared__ float fP[GN*32];
  __shared__ float fF[256*36];
  float acc[GN];
  #pragma unroll
  for (int n=0;n<GN;n++) acc[n]=0.f;
  const float* fb = feat + (size_t)b*CHAN*HWSZ;
  const float* ib = iam + ((size_t)b*NMASK + g*GN)*HWSZ;

  for (int ch=0; ch<32; ch++){
    const int p0 = k0 + ch*32;
    __syncthreads();
    for (int e=t; e<GN*32; e+=256){
      int nl = e >> 5; int pl = e & 31;
      int row = b*NMASK + g*GN + nl;
      float v = ib[(size_t)nl*HWSZ + p0 + pl];
      fP[e] = expf(v - rowmax[row]) * rowinv[row];
    }
    {
      int lane = t & 7; int cbase = t >> 3;
      #pragma unroll
      for (int it=0; it<8; it++){
        int cl = it*32 + cbase;
        float4 v = *(const float4*)&fb[(size_t)cl*HWSZ + p0 + lane*4];
        *(float4*)&fF[cl*36 + lane*4] = v;
      }
    }
    __syncthreads();
    float4 ff[8];
    #pragma unroll
    for (int q=0;q<8;q++) ff[q] = *(const float4*)&fF[t*36 + q*4];
    #pragma unroll
    for (int n=0;n<GN;n++){
      float a = acc[n];
      #pragma unroll
      for (int q=0;q<8;q++){
        float4 pv = *(const float4*)&fP[n*32 + q*4];
        a = fmaf(pv.x, ff[q].x, a); a = fmaf(pv.y, ff[q].y, a);
        a = fmaf(pv.z, ff[q].z, a); a = fmaf(pv.w, ff[q].w, a);
      }
      acc[n]=a;
    }
  }
  #pragma unroll
  for (int n=0;n<GN;n++)
    partial[(((size_t)b*SPLIT + s)*NMASK + g*GN + n)*CHAN + t] = acc[n];
}

// ---------------- reduce partials + fc + heads ----------------
__global__ __launch_bounds__(256) void fc_head_kernel(
  const float* __restrict__ partial,
  const float* __restrict__ fc_w, const float* __restrict__ fc_b,
  const float* __restrict__ cls_w, const float* __restrict__ cls_b,
  const float* __restrict__ mk_w, const float* __restrict__ mk_b,
  const float* __restrict__ obj_w, const float* __restrict__ obj_b,
  float* __restrict__ dout)
{
  const int n = blockIdx.x;
  const int b = blockIdx.y;
  const int t = threadIdx.x;
  __shared__ float xs[256];
  __shared__ float xr[256];
  __shared__ float red[256];
  float x = 0.f;
  for (int s=0;s<SPLIT;s++)
    x += partial[(((size_t)b*SPLIT+s)*NMASK + n)*CHAN + t];
  xs[t] = x;
  __syncthreads();
  float y = fc_b[t];
  const float* wr = fc_w + (size_t)t*CHAN;
  for (int k=0;k<CHAN;k+=4){
    float4 w4 = *(const float4*)&wr[k];
    y = fmaf(xs[k],w4.x,y); y=fmaf(xs[k+1],w4.y,y);
    y = fmaf(xs[k+2],w4.z,y); y=fmaf(xs[k+3],w4.w,y);
  }
  y = fmaxf(y, 0.f);
  xr[t] = y;
  __syncthreads();
  if (t < KD){
    float ka = mk_b[t];
    const float* mr = mk_w + (size_t)t*CHAN;
    for (int k=0;k<CHAN;k+=4){
      float4 w4 = *(const float4*)&mr[k];
      ka = fmaf(xr[k],w4.x,ka); ka=fmaf(xr[k+1],w4.y,ka);
      ka = fmaf(xr[k+2],w4.z,ka); ka=fmaf(xr[k+3],w4.w,ka);
    }
    dout[OFF_KERNEL + ((size_t)b*NMASK + n)*KD + t] = ka;
  }
  red[t] = xr[t] * cls_w[t];
  __syncthreads();
  for (int s2=128;s2>0;s2>>=1){ if(t<s2) red[t]+=red[t+s2]; __syncthreads(); }
  if (t==0) dout[OFF_LOGITS + (size_t)b*NMASK + n] = red[0] + cls_b[0];
  __syncthreads();
  red[t] = xr[t] * obj_w[t];
  __syncthreads();
  for (int s2=128;s2>0;s2>>=1){ if(t<s2) red[t]+=red[t+s2]; __syncthreads(); }
  if (t==0) dout[OFF_SCORES + (size_t)b*NMASK + n] = red[0] + obj_b[0];
}

extern "C" void kernel_launch(void* const* d_in, const int* in_sizes, int n_in,
                              void* d_out, int out_size, void* d_ws, size_t ws_size,
                              hipStream_t stream)
{
  const float* feat   = (const float*)d_in[0];
  const float* conv_w = (const float*)d_in[1];
  const float* conv_b = (const float*)d_in[2];
  // d_in[3] = softmax_bias: scalar shift, softmax-invariant -> unused
  const float* fc_w   = (const float*)d_in[4];
  const float* fc_b   = (const float*)d_in[5];
  const float* cls_w  = (const float*)d_in[6];
  const float* cls_b  = (const float*)d_in[7];
  const float* mk_w   = (const float*)d_in[8];
  const float* mk_b   = (const float*)d_in[9];
  const float* obj_w  = (const float*)d_in[10];
  const float* obj_b  = (const float*)d_in[11];
  float* dout = (float*)d_out;
  float* iam  = dout + OFF_IAM;

  float* rowmax  = (float*)d_ws;
  float* rowinv  = rowmax + 800;
  float* partial = rowinv + 800;   // 8*16*100*256 floats = 13.1 MB

  conv_kernel<<<dim3(4,25,8), 256, 0, stream>>>(feat, conv_w, conv_b, iam);
  softmax_stats_kernel<<<dim3(800), 256, 0, stream>>>(iam, rowmax, rowinv);
  einsum_kernel<<<dim3(SPLIT,4,8), 256, 0, stream>>>(feat, iam, rowmax, rowinv, partial);
  fc_head_kernel<<<dim3(NMASK,BATCH), 256, 0, stream>>>(partial, fc_w, fc_b,
      cls_w, cls_b, mk_w, mk_b, obj_w, obj_b, dout);
}

// Round 3
// 611.089 us; speedup vs baseline: 3.6336x; 3.6336x over previous
//
#include <hip/hip_runtime.h>
#include <math.h>

#define BATCH 8
#define CHAN 256
#define HH 128
#define WW 128
#define NMASK 100
#define HWSZ (HH*WW)
#define KD 128
#define SPLIT 16
#define GN 25

// d_out layout: [logits 800][kernel 102400][scores 800][iam 13107200]
#define OFF_LOGITS 0
#define OFF_KERNEL 800
#define OFF_SCORES (800 + 800*KD)
#define OFF_IAM    (OFF_SCORES + 800)

typedef __attribute__((ext_vector_type(8))) short bf16x8;
typedef __attribute__((ext_vector_type(8))) unsigned short ushort8;
typedef __attribute__((ext_vector_type(4))) float f32x4;

__device__ __forceinline__ unsigned short f2bf(float f){
  unsigned int u = __float_as_uint(f);
  u += 0x7fffu + ((u >> 16) & 1u);
  return (unsigned short)(u >> 16);
}

// ---------------- weight pre-pack into A-fragment order ----------------
// wr[(((tap*8+cc)*7+nt)*64+l)*8+j] = bf16(W[n][c][kh][kw])
//   n = nt*16+(l&15), c = cc*32+(l>>4)*8+j, tap = kh*3+kw; n>=100 -> 0
__global__ __launch_bounds__(256) void wpack_kernel(
    const float* __restrict__ cw, unsigned short* __restrict__ wr)
{
  int i = blockIdx.x*256 + threadIdx.x;
  if (i >= 9*8*7*64*8) return;
  int j = i & 7;
  int l = (i >> 3) & 63;
  int rest = i >> 9;
  int nt = rest % 7;
  int cc8 = rest / 7;
  int cc = cc8 & 7;
  int tap = cc8 >> 3;
  int n = nt*16 + (l & 15);
  int c = cc*32 + (l >> 4)*8 + j;
  float v = 0.f;
  if (n < NMASK) v = cw[((size_t)n*CHAN + c)*9 + tap];
  wr[i] = f2bf(v);
}

// ---------------- conv 3x3 as implicit-GEMM bf16 MFMA ----------------
// grid (128 h-rows, 8 batch), 256 threads = 4 waves
// block output: 112 masks (7 M-tiles) x 128 cols (8 N-tiles); wave w owns
// p-tiles {2w, 2w+1} x all 7 n-tiles.
#define LDSX 40   // channel dim padded 32->40: uniform bank spread for b128 r/w
__global__ __launch_bounds__(256) void conv_mfma_kernel(
    const float* __restrict__ feat, const unsigned short* __restrict__ wr,
    const float* __restrict__ cb, float* __restrict__ out_iam)
{
  const int h = blockIdx.x;
  const int b = blockIdx.y;
  const int t = threadIdx.x;
  const int w = t >> 6;
  const int l = t & 63;
  const int lx = l & 15;
  const int lg = l >> 4;

  __shared__ unsigned short lds[3*132*LDSX];

  f32x4 acc[7][2];
  #pragma unroll
  for (int nt=0;nt<7;nt++)
    #pragma unroll
    for (int pi=0;pi<2;pi++) acc[nt][pi] = (f32x4){0.f,0.f,0.f,0.f};

  const float* fb = feat + (size_t)b*CHAN*HWSZ;

  for (int cc=0; cc<8; ++cc){
    const int c0 = cc*32;
    __syncthreads();
    // stage 32 channels x 3 rows x 130 cols (with zero halo) as bf16
    // group gi = (kh*4+cg)*130 + xh ; one ds_write_b128 (8 channels) per group
    for (int gi = t; gi < 1560; gi += 256){
      int xh = gi % 130;
      int q  = gi / 130;
      int cg = q & 3;
      int kh = q >> 2;
      int row = h + kh - 1;
      int x   = xh - 1;
      bool ok = ((unsigned)row < 128u) & ((unsigned)x < 128u);
      const float* src = fb + (size_t)(c0 + cg*8)*HWSZ + row*WW + x;
      ushort8 u;
      #pragma unroll
      for (int j=0;j<8;j++){
        float v = ok ? src[(size_t)j*HWSZ] : 0.f;
        u[j] = f2bf(v);
      }
      *(ushort8*)&lds[(kh*132 + xh)*LDSX + cg*8] = u;
    }
    __syncthreads();

    const unsigned short* wbase = wr + ((size_t)cc*7*64 + l)*8;
    #pragma unroll 1
    for (int tap=0; tap<9; ++tap){
      const int kh = tap / 3;
      const int kw = tap - kh*3;
      bf16x8 a[7];
      #pragma unroll
      for (int nt=0; nt<7; nt++)
        a[nt] = *(const bf16x8*)(wbase + ((size_t)tap*8*7 + nt)*64*8);
      bf16x8 bfv[2];
      #pragma unroll
      for (int pi=0; pi<2; pi++){
        int xh = (w*2+pi)*16 + lx + kw;   // = x + kw, halo offset +1 built in
        bfv[pi] = *(const bf16x8*)&lds[(kh*132 + xh)*LDSX + lg*8];
      }
      #pragma unroll
      for (int nt=0; nt<7; nt++)
        #pragma unroll
        for (int pi=0; pi<2; pi++)
          acc[nt][pi] = __builtin_amdgcn_mfma_f32_16x16x32_bf16(
              a[nt], bfv[pi], acc[nt][pi], 0, 0, 0);
    }
  }

  // epilogue: D col = lane&15 (spatial x), row = (lane>>4)*4 + r (mask n)
  #pragma unroll
  for (int nt=0; nt<7; nt++){
    const int n0 = nt*16 + lg*4;
    #pragma unroll
    for (int pi=0; pi<2; pi++){
      const int x = (w*2+pi)*16 + lx;
      #pragma unroll
      for (int r=0; r<4; r++){
        int n = n0 + r;
        if (n < NMASK)
          out_iam[((size_t)b*NMASK + n)*HWSZ + h*WW + x] = acc[nt][pi][r] + cb[n];
      }
    }
  }
}

// ---------------- softmax row stats (max, 1/sumexp) ----------------
__global__ __launch_bounds__(256) void softmax_stats_kernel(
    const float* __restrict__ iam, float* __restrict__ rowmax, float* __restrict__ rowinv)
{
  const int row = blockIdx.x;     // b*100+n
  const int t = threadIdx.x;
  const float* p = iam + (size_t)row*HWSZ;
  __shared__ float red[256];
  float m = -1e30f;
  for (int it=0; it<16; it++){
    float4 v = *(const float4*)&p[(it*256+t)*4];
    m = fmaxf(m, fmaxf(fmaxf(v.x,v.y), fmaxf(v.z,v.w)));
  }
  red[t] = m; __syncthreads();
  for (int s=128;s>0;s>>=1){ if (t<s) red[t]=fmaxf(red[t],red[t+s]); __syncthreads(); }
  m = red[0]; __syncthreads();
  float sum=0.f;
  for (int it=0; it<16; it++){
    float4 v = *(const float4*)&p[(it*256+t)*4];
    sum += expf(v.x-m)+expf(v.y-m)+expf(v.z-m)+expf(v.w-m);
  }
  red[t]=sum; __syncthreads();
  for (int s=128;s>0;s>>=1){ if (t<s) red[t]+=red[t+s]; __syncthreads(); }
  if (t==0){ rowmax[row]=m; rowinv[row]=1.0f/red[0]; }
}

// ---------------- einsum: inst0[b,n,c] = sum_p prob[b,n,p]*feat[b,c,p] ----------------
__global__ __launch_bounds__(256) void einsum_kernel(
  const float* __restrict__ feat, const float* __restrict__ iam,
  const float* __restrict__ rowmax, const float* __restrict__ rowinv,
  float* __restrict__ partial)
{
  const int s = blockIdx.x;
  const int g = blockIdx.y;
  const int b = blockIdx.z;
  const int t = threadIdx.x;
  const int k0 = s*1024;
  __shared__ float fP[GN*32];
  __shared__ float fF[256*36];
  float acc[GN];
  #pragma unroll
  for (int n=0;n<GN;n++) acc[n]=0.f;
  const float* fb = feat + (size_t)b*CHAN*HWSZ;
  const float* ib = iam + ((size_t)b*NMASK + g*GN)*HWSZ;

  for (int ch=0; ch<32; ch++){
    const int p0 = k0 + ch*32;
    __syncthreads();
    for (int e=t; e<GN*32; e+=256){
      int nl = e >> 5; int pl = e & 31;
      int row = b*NMASK + g*GN + nl;
      float v = ib[(size_t)nl*HWSZ + p0 + pl];
      fP[e] = expf(v - rowmax[row]) * rowinv[row];
    }
    {
      int lane = t & 7; int cbase = t >> 3;
      #pragma unroll
      for (int it=0; it<8; it++){
        int cl = it*32 + cbase;
        float4 v = *(const float4*)&fb[(size_t)cl*HWSZ + p0 + lane*4];
        *(float4*)&fF[cl*36 + lane*4] = v;
      }
    }
    __syncthreads();
    float4 ff[8];
    #pragma unroll
    for (int q=0;q<8;q++) ff[q] = *(const float4*)&fF[t*36 + q*4];
    #pragma unroll
    for (int n=0;n<GN;n++){
      float a = acc[n];
      #pragma unroll
      for (int q=0;q<8;q++){
        float4 pv = *(const float4*)&fP[n*32 + q*4];
        a = fmaf(pv.x, ff[q].x, a); a = fmaf(pv.y, ff[q].y, a);
        a = fmaf(pv.z, ff[q].z, a); a = fmaf(pv.w, ff[q].w, a);
      }
      acc[n]=a;
    }
  }
  #pragma unroll
  for (int n=0;n<GN;n++)
    partial[(((size_t)b*SPLIT + s)*NMASK + g*GN + n)*CHAN + t] = acc[n];
}

// ---------------- reduce partials + fc + heads ----------------
__global__ __launch_bounds__(256) void fc_head_kernel(
  const float* __restrict__ partial,
  const float* __restrict__ fc_w, const float* __restrict__ fc_b,
  const float* __restrict__ cls_w, const float* __restrict__ cls_b,
  const float* __restrict__ mk_w, const float* __restrict__ mk_b,
  const float* __restrict__ obj_w, const float* __restrict__ obj_b,
  float* __restrict__ dout)
{
  const int n = blockIdx.x;
  const int b = blockIdx.y;
  const int t = threadIdx.x;
  __shared__ float xs[256];
  __shared__ float xr[256];
  __shared__ float red[256];
  float x = 0.f;
  for (int s=0;s<SPLIT;s++)
    x += partial[(((size_t)b*SPLIT+s)*NMASK + n)*CHAN + t];
  xs[t] = x;
  __syncthreads();
  float y = fc_b[t];
  const float* wr2 = fc_w + (size_t)t*CHAN;
  for (int k=0;k<CHAN;k+=4){
    float4 w4 = *(const float4*)&wr2[k];
    y = fmaf(xs[k],w4.x,y); y=fmaf(xs[k+1],w4.y,y);
    y = fmaf(xs[k+2],w4.z,y); y=fmaf(xs[k+3],w4.w,y);
  }
  y = fmaxf(y, 0.f);
  xr[t] = y;
  __syncthreads();
  if (t < KD){
    float ka = mk_b[t];
    const float* mr = mk_w + (size_t)t*CHAN;
    for (int k=0;k<CHAN;k+=4){
      float4 w4 = *(const float4*)&mr[k];
      ka = fmaf(xr[k],w4.x,ka); ka=fmaf(xr[k+1],w4.y,ka);
      ka = fmaf(xr[k+2],w4.z,ka); ka=fmaf(xr[k+3],w4.w,ka);
    }
    dout[OFF_KERNEL + ((size_t)b*NMASK + n)*KD + t] = ka;
  }
  red[t] = xr[t] * cls_w[t];
  __syncthreads();
  for (int s2=128;s2>0;s2>>=1){ if(t<s2) red[t]+=red[t+s2]; __syncthreads(); }
  if (t==0) dout[OFF_LOGITS + (size_t)b*NMASK + n] = red[0] + cls_b[0];
  __syncthreads();
  red[t] = xr[t] * obj_w[t];
  __syncthreads();
  for (int s2=128;s2>0;s2>>=1){ if(t<s2) red[t]+=red[t+s2]; __syncthreads(); }
  if (t==0) dout[OFF_SCORES + (size_t)b*NMASK + n] = red[0] + obj_b[0];
}

extern "C" void kernel_launch(void* const* d_in, const int* in_sizes, int n_in,
                              void* d_out, int out_size, void* d_ws, size_t ws_size,
                              hipStream_t stream)
{
  const float* feat   = (const float*)d_in[0];
  const float* conv_w = (const float*)d_in[1];
  const float* conv_b = (const float*)d_in[2];
  // d_in[3] = softmax_bias: scalar shift, softmax-invariant -> unused
  const float* fc_w   = (const float*)d_in[4];
  const float* fc_b   = (const float*)d_in[5];
  const float* cls_w  = (const float*)d_in[6];
  const float* cls_b  = (const float*)d_in[7];
  const float* mk_w   = (const float*)d_in[8];
  const float* mk_b   = (const float*)d_in[9];
  const float* obj_w  = (const float*)d_in[10];
  const float* obj_b  = (const float*)d_in[11];
  float* dout = (float*)d_out;
  float* iam  = dout + OFF_IAM;

  float* rowmax  = (float*)d_ws;
  float* rowinv  = rowmax + 800;
  float* partial = rowinv + 800;                       // 3,276,800 floats = 13.1 MB
  unsigned short* wr = (unsigned short*)(partial + (size_t)BATCH*SPLIT*NMASK*CHAN); // 516 KB

  wpack_kernel<<<dim3((9*8*7*64*8 + 255)/256), 256, 0, stream>>>(conv_w, wr);
  conv_mfma_kernel<<<dim3(128, 8), 256, 0, stream>>>(feat, wr, conv_b, iam);
  softmax_stats_kernel<<<dim3(800), 256, 0, stream>>>(iam, rowmax, rowinv);
  einsum_kernel<<<dim3(SPLIT,4,8), 256, 0, stream>>>(feat, iam, rowmax, rowinv, partial);
  fc_head_kernel<<<dim3(NMASK,BATCH), 256, 0, stream>>>(partial, fc_w, fc_b,
      cls_w, cls_b, mk_w, mk_b, obj_w, obj_b, dout);
}

// Round 4
// 351.086 us; speedup vs baseline: 6.3245x; 1.7406x over previous
//
#include <hip/hip_runtime.h>
#include <math.h>

#define BATCH 8
#define CHAN 256
#define HH 128
#define WW 128
#define NMASK 100
#define HWSZ (HH*WW)
#define KD 128

// d_out layout: [logits 800][kernel 102400][scores 800][iam 13107200]
#define OFF_LOGITS 0
#define OFF_KERNEL 800
#define OFF_SCORES (800 + 800*KD)
#define OFF_IAM    (OFF_SCORES + 800)

typedef __attribute__((ext_vector_type(8))) short bf16x8;
typedef __attribute__((ext_vector_type(8))) unsigned short ushort8;
typedef __attribute__((ext_vector_type(4))) float f32x4;

__device__ __forceinline__ unsigned short f2bf(float f){
  unsigned int u = __float_as_uint(f);
  u += 0x7fffu + ((u >> 16) & 1u);
  return (unsigned short)(u >> 16);
}

// ---------------- weight pre-pack into A-fragment order ----------------
__global__ __launch_bounds__(256) void wpack_kernel(
    const float* __restrict__ cw, unsigned short* __restrict__ wr)
{
  int i = blockIdx.x*256 + threadIdx.x;
  if (i >= 9*8*7*64*8) return;
  int j = i & 7;
  int l = (i >> 3) & 63;
  int rest = i >> 9;
  int nt = rest % 7;
  int cc8 = rest / 7;
  int cc = cc8 & 7;
  int tap = cc8 >> 3;
  int n = nt*16 + (l & 15);
  int c = cc*32 + (l >> 4)*8 + j;
  float v = 0.f;
  if (n < NMASK) v = cw[((size_t)n*CHAN + c)*9 + tap];
  wr[i] = f2bf(v);
}

// ---------------- conv 3x3 as implicit-GEMM bf16 MFMA ----------------
#define LDSX 40
__global__ __launch_bounds__(256) void conv_mfma_kernel(
    const float* __restrict__ feat, const unsigned short* __restrict__ wr,
    const float* __restrict__ cb, float* __restrict__ out_iam)
{
  const int h = blockIdx.x;
  const int b = blockIdx.y;
  const int t = threadIdx.x;
  const int w = t >> 6;
  const int l = t & 63;
  const int lx = l & 15;
  const int lg = l >> 4;

  __shared__ unsigned short lds[3*132*LDSX];

  f32x4 acc[7][2];
  #pragma unroll
  for (int nt=0;nt<7;nt++)
    #pragma unroll
    for (int pi=0;pi<2;pi++) acc[nt][pi] = (f32x4){0.f,0.f,0.f,0.f};

  const float* fb = feat + (size_t)b*CHAN*HWSZ;

  for (int cc=0; cc<8; ++cc){
    const int c0 = cc*32;
    __syncthreads();
    for (int gi = t; gi < 1560; gi += 256){
      int xh = gi % 130;
      int q  = gi / 130;
      int cg = q & 3;
      int kh = q >> 2;
      int row = h + kh - 1;
      int x   = xh - 1;
      bool ok = ((unsigned)row < 128u) & ((unsigned)x < 128u);
      const float* src = fb + (size_t)(c0 + cg*8)*HWSZ + row*WW + x;
      ushort8 u;
      #pragma unroll
      for (int j=0;j<8;j++){
        float v = ok ? src[(size_t)j*HWSZ] : 0.f;
        u[j] = f2bf(v);
      }
      *(ushort8*)&lds[(kh*132 + xh)*LDSX + cg*8] = u;
    }
    __syncthreads();

    const unsigned short* wbase = wr + ((size_t)cc*7*64 + l)*8;
    #pragma unroll 1
    for (int tap=0; tap<9; ++tap){
      const int kh = tap / 3;
      const int kw = tap - kh*3;
      bf16x8 a[7];
      #pragma unroll
      for (int nt=0; nt<7; nt++)
        a[nt] = *(const bf16x8*)(wbase + ((size_t)tap*8*7 + nt)*64*8);
      bf16x8 bfv[2];
      #pragma unroll
      for (int pi=0; pi<2; pi++){
        int xh = (w*2+pi)*16 + lx + kw;
        bfv[pi] = *(const bf16x8*)&lds[(kh*132 + xh)*LDSX + lg*8];
      }
      #pragma unroll
      for (int nt=0; nt<7; nt++)
        #pragma unroll
        for (int pi=0; pi<2; pi++)
          acc[nt][pi] = __builtin_amdgcn_mfma_f32_16x16x32_bf16(
              a[nt], bfv[pi], acc[nt][pi], 0, 0, 0);
    }
  }

  #pragma unroll
  for (int nt=0; nt<7; nt++){
    const int n0 = nt*16 + lg*4;
    #pragma unroll
    for (int pi=0; pi<2; pi++){
      const int x = (w*2+pi)*16 + lx;
      #pragma unroll
      for (int r=0; r<4; r++){
        int n = n0 + r;
        if (n < NMASK)
          out_iam[((size_t)b*NMASK + n)*HWSZ + h*WW + x] = acc[nt][pi][r] + cb[n];
      }
    }
  }
}

// ---------------- softmax row stats (max, 1/sumexp) ----------------
__global__ __launch_bounds__(256) void softmax_stats_kernel(
    const float* __restrict__ iam, float* __restrict__ rowmax, float* __restrict__ rowinv)
{
  const int row = blockIdx.x;
  const int t = threadIdx.x;
  const float* p = iam + (size_t)row*HWSZ;
  __shared__ float red[256];
  float m = -1e30f;
  for (int it=0; it<16; it++){
    float4 v = *(const float4*)&p[(it*256+t)*4];
    m = fmaxf(m, fmaxf(fmaxf(v.x,v.y), fmaxf(v.z,v.w)));
  }
  red[t] = m; __syncthreads();
  for (int s=128;s>0;s>>=1){ if (t<s) red[t]=fmaxf(red[t],red[t+s]); __syncthreads(); }
  m = red[0]; __syncthreads();
  float sum=0.f;
  for (int it=0; it<16; it++){
    float4 v = *(const float4*)&p[(it*256+t)*4];
    sum += expf(v.x-m)+expf(v.y-m)+expf(v.z-m)+expf(v.w-m);
  }
  red[t]=sum; __syncthreads();
  for (int s=128;s>0;s>>=1){ if (t<s) red[t]+=red[t+s]; __syncthreads(); }
  if (t==0){ rowmax[row]=m; rowinv[row]=1.0f/red[0]; }
}

// ---------------- einsum as MFMA: partial[s][b][n][c] += P(16..)·F^T ----------------
// grid (KSPLIT, 1, 8), 256 thr = 4 waves. Wave w: channel tiles w*64..+63 (4 B-frags),
// all 7 mask tiles (A-frags computed in-register from iam: exp(v-m)*rinv -> bf16).
// No LDS, no barriers: both operands are K(=p)-contiguous in global memory.
__global__ __launch_bounds__(256) void einsum_mfma_kernel(
  const float* __restrict__ feat, const float* __restrict__ iam,
  const float* __restrict__ rowmax, const float* __restrict__ rowinv,
  float* __restrict__ partial)
{
  const int s = blockIdx.x;
  const int nsplit = gridDim.x;
  const int KC = HWSZ / nsplit;
  const int b = blockIdx.z;
  const int t = threadIdx.x;
  const int w = t >> 6;
  const int l = t & 63;
  const int lx = l & 15;
  const int lg = l >> 4;

  f32x4 acc[7][4];
  #pragma unroll
  for (int nt=0;nt<7;nt++)
    #pragma unroll
    for (int j=0;j<4;j++) acc[nt][j] = (f32x4){0.f,0.f,0.f,0.f};

  // per-lane hoisted row stats (A rows: n = nt*16 + (l&15), clamped)
  int   rown[7];
  float m_[7], r_[7];
  #pragma unroll
  for (int nt=0;nt<7;nt++){
    int row = nt*16 + lx;
    if (row >= NMASK) row = NMASK-1;
    rown[nt] = row;
    m_[nt] = rowmax[b*NMASK + row];
    r_[nt] = rowinv[b*NMASK + row];
  }

  const float* fb = feat + (size_t)b*CHAN*HWSZ;
  const float* ib = iam  + (size_t)b*NMASK*HWSZ;

  #pragma unroll 1
  for (int ks=0; ks<KC/32; ++ks){
    const int p0 = s*KC + ks*32 + lg*8;
    bf16x8 afr[7];
    #pragma unroll
    for (int nt=0;nt<7;nt++){
      const float* ap = ib + (size_t)rown[nt]*HWSZ + p0;
      float4 a0 = *(const float4*)ap;
      float4 a1 = *(const float4*)(ap+4);
      const float m = m_[nt], rv = r_[nt];
      ushort8 u;
      u[0]=f2bf(__expf(a0.x-m)*rv); u[1]=f2bf(__expf(a0.y-m)*rv);
      u[2]=f2bf(__expf(a0.z-m)*rv); u[3]=f2bf(__expf(a0.w-m)*rv);
      u[4]=f2bf(__expf(a1.x-m)*rv); u[5]=f2bf(__expf(a1.y-m)*rv);
      u[6]=f2bf(__expf(a1.z-m)*rv); u[7]=f2bf(__expf(a1.w-m)*rv);
      afr[nt] = *(bf16x8*)&u;
    }
    bf16x8 bfr[4];
    #pragma unroll
    for (int j=0;j<4;j++){
      const float* fp = fb + (size_t)(w*64 + j*16 + lx)*HWSZ + p0;
      float4 b0 = *(const float4*)fp;
      float4 b1 = *(const float4*)(fp+4);
      ushort8 u;
      u[0]=f2bf(b0.x); u[1]=f2bf(b0.y); u[2]=f2bf(b0.z); u[3]=f2bf(b0.w);
      u[4]=f2bf(b1.x); u[5]=f2bf(b1.y); u[6]=f2bf(b1.z); u[7]=f2bf(b1.w);
      bfr[j] = *(bf16x8*)&u;
    }
    #pragma unroll
    for (int nt=0;nt<7;nt++)
      #pragma unroll
      for (int j=0;j<4;j++)
        acc[nt][j] = __builtin_amdgcn_mfma_f32_16x16x32_bf16(
            afr[nt], bfr[j], acc[nt][j], 0, 0, 0);
  }

  // D: row(mask) = lg*4 + r, col(channel) = lx
  #pragma unroll
  for (int nt=0;nt<7;nt++){
    #pragma unroll
    for (int j=0;j<4;j++){
      const int c = w*64 + j*16 + lx;
      #pragma unroll
      for (int r=0;r<4;r++){
        int n = nt*16 + lg*4 + r;
        if (n < NMASK)
          partial[(((size_t)b*nsplit + s)*NMASK + n)*CHAN + c] = acc[nt][j][r];
      }
    }
  }
}

// ---------------- reduce partials + fc + heads ----------------
__global__ __launch_bounds__(256) void fc_head_kernel(
  const float* __restrict__ partial, int nsplit,
  const float* __restrict__ fc_w, const float* __restrict__ fc_b,
  const float* __restrict__ cls_w, const float* __restrict__ cls_b,
  const float* __restrict__ mk_w, const float* __restrict__ mk_b,
  const float* __restrict__ obj_w, const float* __restrict__ obj_b,
  float* __restrict__ dout)
{
  const int n = blockIdx.x;
  const int b = blockIdx.y;
  const int t = threadIdx.x;
  __shared__ float xs[256];
  __shared__ float xr[256];
  __shared__ float red[256];
  float x = 0.f;
  for (int s=0;s<nsplit;s++)
    x += partial[(((size_t)b*nsplit+s)*NMASK + n)*CHAN + t];
  xs[t] = x;
  __syncthreads();
  float y = fc_b[t];
  const float* wr2 = fc_w + (size_t)t*CHAN;
  for (int k=0;k<CHAN;k+=4){
    float4 w4 = *(const float4*)&wr2[k];
    y = fmaf(xs[k],w4.x,y); y=fmaf(xs[k+1],w4.y,y);
    y = fmaf(xs[k+2],w4.z,y); y=fmaf(xs[k+3],w4.w,y);
  }
  y = fmaxf(y, 0.f);
  xr[t] = y;
  __syncthreads();
  if (t < KD){
    float ka = mk_b[t];
    const float* mr = mk_w + (size_t)t*CHAN;
    for (int k=0;k<CHAN;k+=4){
      float4 w4 = *(const float4*)&mr[k];
      ka = fmaf(xr[k],w4.x,ka); ka=fmaf(xr[k+1],w4.y,ka);
      ka = fmaf(xr[k+2],w4.z,ka); ka=fmaf(xr[k+3],w4.w,ka);
    }
    dout[OFF_KERNEL + ((size_t)b*NMASK + n)*KD + t] = ka;
  }
  red[t] = xr[t] * cls_w[t];
  __syncthreads();
  for (int s2=128;s2>0;s2>>=1){ if(t<s2) red[t]+=red[t+s2]; __syncthreads(); }
  if (t==0) dout[OFF_LOGITS + (size_t)b*NMASK + n] = red[0] + cls_b[0];
  __syncthreads();
  red[t] = xr[t] * obj_w[t];
  __syncthreads();
  for (int s2=128;s2>0;s2>>=1){ if(t<s2) red[t]+=red[t+s2]; __syncthreads(); }
  if (t==0) dout[OFF_SCORES + (size_t)b*NMASK + n] = red[0] + obj_b[0];
}

extern "C" void kernel_launch(void* const* d_in, const int* in_sizes, int n_in,
                              void* d_out, int out_size, void* d_ws, size_t ws_size,
                              hipStream_t stream)
{
  const float* feat   = (const float*)d_in[0];
  const float* conv_w = (const float*)d_in[1];
  const float* conv_b = (const float*)d_in[2];
  // d_in[3] = softmax_bias: scalar shift, softmax-invariant -> unused
  const float* fc_w   = (const float*)d_in[4];
  const float* fc_b   = (const float*)d_in[5];
  const float* cls_w  = (const float*)d_in[6];
  const float* cls_b  = (const float*)d_in[7];
  const float* mk_w   = (const float*)d_in[8];
  const float* mk_b   = (const float*)d_in[9];
  const float* obj_w  = (const float*)d_in[10];
  const float* obj_b  = (const float*)d_in[11];
  float* dout = (float*)d_out;
  float* iam  = dout + OFF_IAM;

  // pick K-split by available workspace: need = 6400 + ks*8*100*256*4 + 516096
  const size_t fixed = 1600*sizeof(float) + 9*8*7*64*8*sizeof(unsigned short);
  int ksplit = 16;
  if (ws_size >= fixed + (size_t)64*BATCH*NMASK*CHAN*4) ksplit = 64;
  else if (ws_size >= fixed + (size_t)32*BATCH*NMASK*CHAN*4) ksplit = 32;

  float* rowmax  = (float*)d_ws;
  float* rowinv  = rowmax + 800;
  float* partial = rowinv + 800;
  unsigned short* wr = (unsigned short*)(partial + (size_t)ksplit*BATCH*NMASK*CHAN);

  wpack_kernel<<<dim3((9*8*7*64*8 + 255)/256), 256, 0, stream>>>(conv_w, wr);
  conv_mfma_kernel<<<dim3(128, 8), 256, 0, stream>>>(feat, wr, conv_b, iam);
  softmax_stats_kernel<<<dim3(800), 256, 0, stream>>>(iam, rowmax, rowinv);
  einsum_mfma_kernel<<<dim3(ksplit, 1, 8), 256, 0, stream>>>(feat, iam, rowmax, rowinv, partial);
  fc_head_kernel<<<dim3(NMASK,BATCH), 256, 0, stream>>>(partial, ksplit, fc_w, fc_b,
      cls_w, cls_b, mk_w, mk_b, obj_w, obj_b, dout);
}